// Round 1
// baseline (338.317 us; speedup 1.0000x reference)
//
#include <hip/hip_runtime.h>
#include <math.h>

#define D_FEAT 128

// ---------------------------------------------------------------------------
// 1. Per-node inverse L2 norm: one wave (64 lanes) per node, float2 per lane.
// ---------------------------------------------------------------------------
__global__ void invnorm_kernel(const float* __restrict__ feat,
                               float* __restrict__ invn, int n_nodes) {
    int node = (blockIdx.x * blockDim.x + threadIdx.x) >> 6;
    int lane = threadIdx.x & 63;
    if (node >= n_nodes) return;
    const float2* f2 = (const float2*)feat;
    float2 f = f2[node * 64 + lane];
    float ss = f.x * f.x + f.y * f.y;
    #pragma unroll
    for (int off = 1; off < 64; off <<= 1)
        ss += __shfl_xor(ss, off, 64);
    if (lane == 0)
        invn[node] = 1.0f / fmaxf(sqrtf(ss), 1e-12f);
}

// ---------------------------------------------------------------------------
// 2. Per-edge scaled cosine: 32 lanes per edge, float4 per lane.
//    Also builds the dst histogram (fused).
// ---------------------------------------------------------------------------
__global__ void edge_dot_kernel(const float* __restrict__ feat,
                                const int* __restrict__ src,
                                const int* __restrict__ dst,
                                const float* __restrict__ beta,
                                const float* __restrict__ invn,
                                float* __restrict__ e_val,
                                int* __restrict__ count,
                                int n_edges) {
    int gtid = blockIdx.x * blockDim.x + threadIdx.x;
    int edge = gtid >> 5;
    int lane = threadIdx.x & 31;
    if (edge >= n_edges) return;
    int s = src[edge];
    int d = dst[edge];
    const float4* f4 = (const float4*)feat;
    float4 a = f4[s * 32 + lane];
    float4 b = f4[d * 32 + lane];
    float dot = a.x * b.x + a.y * b.y + a.z * b.z + a.w * b.w;
    #pragma unroll
    for (int off = 1; off < 32; off <<= 1)
        dot += __shfl_xor(dot, off, 32);
    if (lane == 0) {
        e_val[edge] = beta[0] * dot * invn[s] * invn[d];
        atomicAdd(&count[d], 1);
    }
}

// ---------------------------------------------------------------------------
// 3. Exclusive scan of counts -> CSR offsets. Single wave, shuffle scan.
//    10000 elements / 64 lanes = 157 iterations; a few microseconds.
// ---------------------------------------------------------------------------
__global__ void scan_kernel(const int* __restrict__ count,
                            int* __restrict__ offsets, int n) {
    int lane = threadIdx.x;  // launched with 64 threads
    int running = 0;
    for (int base = 0; base < n; base += 64) {
        int i = base + lane;
        int v = (i < n) ? count[i] : 0;
        int sum = v;
        #pragma unroll
        for (int off = 1; off < 64; off <<= 1) {
            int t = __shfl_up(sum, off, 64);
            if (lane >= off) sum += t;
        }
        if (i < n) offsets[i] = running + sum - v;  // exclusive
        running += __shfl(sum, 63, 64);
    }
    if (lane == 0) offsets[n] = running;
}

// ---------------------------------------------------------------------------
// 4. Scatter edges into CSR buckets (src id + e value), atomic cursor per dst.
// ---------------------------------------------------------------------------
__global__ void scatter_kernel(const int* __restrict__ src,
                               const int* __restrict__ dst,
                               const float* __restrict__ e_val,
                               const int* __restrict__ offsets,
                               int* __restrict__ cursor,
                               int* __restrict__ src_sorted,
                               float* __restrict__ e_sorted,
                               int n_edges) {
    int e = blockIdx.x * blockDim.x + threadIdx.x;
    if (e >= n_edges) return;
    int d = dst[e];
    int pos = atomicAdd(&cursor[d], 1);
    int idx = offsets[d] + pos;
    src_sorted[idx] = src[e];
    e_sorted[idx] = e_val[e];
}

// ---------------------------------------------------------------------------
// 5. Per-node softmax + weighted aggregation. One wave per node.
//    Lanes cover the 128 feature dims (float2/lane); edges loop sequentially.
//    No atomics anywhere; writes the full output row.
// ---------------------------------------------------------------------------
__global__ void node_agg_kernel(const float* __restrict__ feat,
                                const int* __restrict__ offsets,
                                const int* __restrict__ src_sorted,
                                const float* __restrict__ e_sorted,
                                float* __restrict__ out,
                                int n_nodes) {
    int node = (blockIdx.x * blockDim.x + threadIdx.x) >> 6;
    int lane = threadIdx.x & 63;
    if (node >= n_nodes) return;
    int beg = offsets[node];
    int end = offsets[node + 1];

    // online-softmax stats over this node's edges
    float m = -INFINITY;
    for (int i = beg + lane; i < end; i += 64)
        m = fmaxf(m, e_sorted[i]);
    #pragma unroll
    for (int off = 1; off < 64; off <<= 1)
        m = fmaxf(m, __shfl_xor(m, off, 64));

    float ssum = 0.0f;
    for (int i = beg + lane; i < end; i += 64)
        ssum += expf(e_sorted[i] - m);
    #pragma unroll
    for (int off = 1; off < 64; off <<= 1)
        ssum += __shfl_xor(ssum, off, 64);
    float inv = (end > beg) ? (1.0f / ssum) : 0.0f;

    const float2* f2 = (const float2*)feat;
    float accx = 0.0f, accy = 0.0f;
    for (int i = beg; i < end; ++i) {
        float p = expf(e_sorted[i] - m) * inv;  // uniform across lanes
        int s = src_sorted[i];                  // broadcast load
        float2 f = f2[s * 64 + lane];
        accx += p * f.x;
        accy += p * f.y;
    }
    ((float2*)out)[node * 64 + lane] = make_float2(accx, accy);
}

// ---------------------------------------------------------------------------
extern "C" void kernel_launch(void* const* d_in, const int* in_sizes, int n_in,
                              void* d_out, int out_size, void* d_ws, size_t ws_size,
                              hipStream_t stream) {
    const float* feat = (const float*)d_in[0];
    const int* src   = (const int*)d_in[1];
    const int* dst   = (const int*)d_in[2];
    const float* beta = (const float*)d_in[3];
    float* out = (float*)d_out;

    const int n_nodes = in_sizes[0] / D_FEAT;
    const int n_edges = in_sizes[1];

    // workspace carve-out (256B-aligned chunks); total ~7.9 MB
    char* ws = (char*)d_ws;
    size_t off = 0;
    auto alloc = [&](size_t bytes) -> void* {
        void* p = ws + off;
        off += (bytes + 255) & ~(size_t)255;
        return p;
    };
    float* invn       = (float*)alloc((size_t)n_nodes * 4);
    float* e_val      = (float*)alloc((size_t)n_edges * 4);
    int*   count      = (int*)  alloc((size_t)n_nodes * 4);
    int*   cursor     = (int*)  alloc((size_t)n_nodes * 4);
    int*   offsets    = (int*)  alloc((size_t)(n_nodes + 1) * 4);
    int*   src_sorted = (int*)  alloc((size_t)n_edges * 4);
    float* e_sorted   = (float*)alloc((size_t)n_edges * 4);

    // ws is re-poisoned to 0xAA before every timed launch -> zero what we need
    hipMemsetAsync(count, 0, (size_t)n_nodes * sizeof(int), stream);
    hipMemsetAsync(cursor, 0, (size_t)n_nodes * sizeof(int), stream);

    invnorm_kernel<<<(n_nodes + 3) / 4, 256, 0, stream>>>(feat, invn, n_nodes);

    int edge_blocks = (int)(((size_t)n_edges * 32 + 255) / 256);
    edge_dot_kernel<<<edge_blocks, 256, 0, stream>>>(feat, src, dst, beta, invn,
                                                     e_val, count, n_edges);

    scan_kernel<<<1, 64, 0, stream>>>(count, offsets, n_nodes);

    scatter_kernel<<<(n_edges + 255) / 256, 256, 0, stream>>>(
        src, dst, e_val, offsets, cursor, src_sorted, e_sorted, n_edges);

    node_agg_kernel<<<(n_nodes + 3) / 4, 256, 0, stream>>>(
        feat, offsets, src_sorted, e_sorted, out, n_nodes);
}

// Round 2
// 250.837 us; speedup vs baseline: 1.3488x; 1.3488x over previous
//
#include <hip/hip_runtime.h>
#include <math.h>

#define D_FEAT 128

// ---------------------------------------------------------------------------
// 1. Normalize: one wave per node. Writes nfeat = feat/||feat|| and the
//    clamped norm so feat[s] can be reconstructed as nfeat[s]*norm[s].
// ---------------------------------------------------------------------------
__global__ void normalize_kernel(const float* __restrict__ feat,
                                 float* __restrict__ nfeat,
                                 float* __restrict__ norm, int n_nodes) {
    int node = (blockIdx.x * blockDim.x + threadIdx.x) >> 6;
    int lane = threadIdx.x & 63;
    if (node >= n_nodes) return;
    const float2* f2 = (const float2*)feat;
    float2 f = f2[node * 64 + lane];
    float ss = f.x * f.x + f.y * f.y;
    #pragma unroll
    for (int off = 1; off < 64; off <<= 1)
        ss += __shfl_xor(ss, off, 64);
    float nm = fmaxf(sqrtf(ss), 1e-12f);
    float inv = 1.0f / nm;
    ((float2*)nfeat)[node * 64 + lane] = make_float2(f.x * inv, f.y * inv);
    if (lane == 0) norm[node] = nm;
}

// ---------------------------------------------------------------------------
// 2. Histogram of dst (int atomics only).
// ---------------------------------------------------------------------------
__global__ void hist_kernel(const int* __restrict__ dst,
                            int* __restrict__ count, int n_edges) {
    int e = blockIdx.x * blockDim.x + threadIdx.x;
    if (e < n_edges) atomicAdd(&count[dst[e]], 1);
}

// ---------------------------------------------------------------------------
// 3. Exclusive scan -> CSR offsets. ONE block of 1024 threads, hierarchical:
//    per-thread chunk sums -> wave shuffle scan -> LDS wave-total scan.
//    (Round-1 version was a single wave doing 157 serialized global loads
//     = 80 us. This is ~2 global round trips.)
// ---------------------------------------------------------------------------
__global__ __launch_bounds__(1024) void scan_kernel(const int* __restrict__ count,
                                                    int* __restrict__ offsets, int n) {
    __shared__ int wsum[16];
    __shared__ int total;
    int t = threadIdx.x;
    const int per = (n + 1023) >> 10;  // 10 for n=10000
    int beg = t * per;
    int end = beg + per;
    if (beg > n) beg = n;
    if (end > n) end = n;
    int local[16];  // per <= 16 supported
    int s = 0;
    for (int i = beg; i < end; ++i) { int v = count[i]; local[i - beg] = v; s += v; }
    int lane = t & 63, wid = t >> 6;
    int incl = s;
    #pragma unroll
    for (int off = 1; off < 64; off <<= 1) {
        int v = __shfl_up(incl, off, 64);
        if (lane >= off) incl += v;
    }
    if (lane == 63) wsum[wid] = incl;
    __syncthreads();
    if (t == 0) {
        int run = 0;
        #pragma unroll
        for (int w = 0; w < 16; ++w) { int v = wsum[w]; wsum[w] = run; run += v; }
        total = run;
    }
    __syncthreads();
    int base = wsum[wid] + (incl - s);  // global exclusive prefix for this chunk
    for (int i = beg; i < end; ++i) { offsets[i] = base; base += local[i - beg]; }
    if (t == 0) offsets[n] = total;
}

// ---------------------------------------------------------------------------
// 4. Scatter src ids into CSR buckets (atomic cursor per dst).
// ---------------------------------------------------------------------------
__global__ void scatter_kernel(const int* __restrict__ src,
                               const int* __restrict__ dst,
                               const int* __restrict__ offsets,
                               int* __restrict__ cursor,
                               int* __restrict__ src_sorted,
                               int n_edges) {
    int e = blockIdx.x * blockDim.x + threadIdx.x;
    if (e >= n_edges) return;
    int d = dst[e];
    int pos = atomicAdd(&cursor[d], 1);
    src_sorted[offsets[d] + pos] = src[e];
}

// ---------------------------------------------------------------------------
// 5. Fused per-node kernel: dot + online softmax + weighted aggregation.
//    One wave per node; dst row pinned in registers (float2/lane); one
//    nfeat row load per edge; src indices/norms batch-loaded (64 at a time)
//    and register-broadcast via shuffle. No float atomics, no e-value
//    round trip through memory.
// ---------------------------------------------------------------------------
__global__ void agg_kernel(const float* __restrict__ nfeat,
                           const float* __restrict__ norm,
                           const float* __restrict__ beta,
                           const int* __restrict__ offsets,
                           const int* __restrict__ src_sorted,
                           float* __restrict__ out, int n_nodes) {
    int node = (blockIdx.x * blockDim.x + threadIdx.x) >> 6;
    int lane = threadIdx.x & 63;
    if (node >= n_nodes) return;
    int beg = offsets[node];
    int end = offsets[node + 1];
    const float2* nf2 = (const float2*)nfeat;
    float2 nd = nf2[node * 64 + lane];
    float b = beta[0];

    float m = -INFINITY, l = 0.0f;
    float ax = 0.0f, ay = 0.0f;

    for (int base = beg; base < end; base += 64) {
        int n_batch = end - base;
        if (n_batch > 64) n_batch = 64;
        int gi = base + lane;
        int idx = (gi < end) ? src_sorted[gi] : 0;
        float nrm = norm[idx];
        for (int j = 0; j < n_batch; ++j) {
            int s = __shfl(idx, j, 64);
            float sn = __shfl(nrm, j, 64);
            float2 f = nf2[s * 64 + lane];
            float part = f.x * nd.x + f.y * nd.y;
            #pragma unroll
            for (int off = 1; off < 64; off <<= 1)
                part += __shfl_xor(part, off, 64);
            float e = b * part;
            float nm = fmaxf(m, e);
            float alpha = expf(m - nm);  // m=-inf on first edge -> alpha=0
            float p = expf(e - nm);
            l = l * alpha + p;
            float w = p * sn;
            ax = ax * alpha + w * f.x;
            ay = ay * alpha + w * f.y;
            m = nm;
        }
    }
    float invl = (l > 0.0f) ? (1.0f / l) : 0.0f;
    ((float2*)out)[node * 64 + lane] = make_float2(ax * invl, ay * invl);
}

// ---------------------------------------------------------------------------
extern "C" void kernel_launch(void* const* d_in, const int* in_sizes, int n_in,
                              void* d_out, int out_size, void* d_ws, size_t ws_size,
                              hipStream_t stream) {
    const float* feat = (const float*)d_in[0];
    const int* src    = (const int*)d_in[1];
    const int* dst    = (const int*)d_in[2];
    const float* beta = (const float*)d_in[3];
    float* out = (float*)d_out;

    const int n_nodes = in_sizes[0] / D_FEAT;
    const int n_edges = in_sizes[1];

    char* ws = (char*)d_ws;
    size_t off = 0;
    auto alloc = [&](size_t bytes) -> void* {
        void* p = ws + off;
        off += (bytes + 255) & ~(size_t)255;
        return p;
    };
    float* nfeat      = (float*)alloc((size_t)n_nodes * D_FEAT * 4);  // 5.12 MB
    float* norm       = (float*)alloc((size_t)n_nodes * 4);
    int*   count      = (int*)  alloc((size_t)n_nodes * 4);
    int*   cursor     = (int*)  alloc((size_t)n_nodes * 4);
    int*   offsets    = (int*)  alloc((size_t)(n_nodes + 1) * 4);
    int*   src_sorted = (int*)  alloc((size_t)n_edges * 4);            // 2.56 MB

    hipMemsetAsync(count, 0, (size_t)n_nodes * sizeof(int), stream);
    hipMemsetAsync(cursor, 0, (size_t)n_nodes * sizeof(int), stream);

    normalize_kernel<<<(n_nodes + 3) / 4, 256, 0, stream>>>(feat, nfeat, norm, n_nodes);

    hist_kernel<<<(n_edges + 255) / 256, 256, 0, stream>>>(dst, count, n_edges);

    scan_kernel<<<1, 1024, 0, stream>>>(count, offsets, n_nodes);

    scatter_kernel<<<(n_edges + 255) / 256, 256, 0, stream>>>(
        src, dst, offsets, cursor, src_sorted, n_edges);

    agg_kernel<<<(n_nodes + 3) / 4, 256, 0, stream>>>(
        nfeat, norm, beta, offsets, src_sorted, out, n_nodes);
}

// Round 3
// 189.599 us; speedup vs baseline: 1.7844x; 1.3230x over previous
//
#include <hip/hip_runtime.h>
#include <math.h>

#define D_FEAT 128

// ---------------------------------------------------------------------------
// 1. Normalize: one wave per node. nfeat = feat/||feat||, norm = clamped norm
//    (so feat[s] = nfeat[s]*norm[s] for the aggregation stage).
// ---------------------------------------------------------------------------
__global__ void normalize_kernel(const float* __restrict__ feat,
                                 float* __restrict__ nfeat,
                                 float* __restrict__ norm, int n_nodes) {
    int node = (blockIdx.x * blockDim.x + threadIdx.x) >> 6;
    int lane = threadIdx.x & 63;
    if (node >= n_nodes) return;
    const float2* f2 = (const float2*)feat;
    float2 f = f2[node * 64 + lane];
    float ss = f.x * f.x + f.y * f.y;
    #pragma unroll
    for (int off = 1; off < 64; off <<= 1)
        ss += __shfl_xor(ss, off, 64);
    float nm = fmaxf(sqrtf(ss), 1e-12f);
    float inv = 1.0f / nm;
    ((float2*)nfeat)[node * 64 + lane] = make_float2(f.x * inv, f.y * inv);
    if (lane == 0) norm[node] = nm;
}

// ---------------------------------------------------------------------------
// 2. Fused dot + histogram/rank. 8 lanes per edge: each group of 8 lanes
//    reads 128B-contiguous chunks of the src and dst rows (full cache-line
//    consumption per instruction), 3-step sub-group shuffle reduce.
//    Leader lane does the ONE atomic pass of the pipeline (rank within dst
//    bucket) — its latency hides behind the 8 outstanding row loads.
// ---------------------------------------------------------------------------
__global__ void dot_rank_kernel(const float* __restrict__ nfeat,
                                const int* __restrict__ src,
                                const int* __restrict__ dst,
                                const float* __restrict__ beta,
                                int* __restrict__ count,
                                unsigned short* __restrict__ rank,
                                float* __restrict__ e_orig,
                                int n_edges) {
    int gtid = blockIdx.x * blockDim.x + threadIdx.x;
    int edge = gtid >> 3;
    int r = threadIdx.x & 7;
    if (edge >= n_edges) return;
    int s = src[edge];
    int d = dst[edge];
    const float4* nf4 = (const float4*)nfeat;
    float part = 0.0f;
    #pragma unroll
    for (int k = 0; k < 4; ++k) {        // 8 lanes x 4 iters x float4 = 128 dims
        float4 a = nf4[s * 32 + k * 8 + r];
        float4 b = nf4[d * 32 + k * 8 + r];
        part += a.x * b.x + a.y * b.y + a.z * b.z + a.w * b.w;
    }
    #pragma unroll
    for (int off = 1; off < 8; off <<= 1)
        part += __shfl_xor(part, off, 8);
    if (r == 0) {
        rank[edge] = (unsigned short)atomicAdd(&count[d], 1);
        e_orig[edge] = beta[0] * part;
    }
}

// ---------------------------------------------------------------------------
// 3. Exclusive scan -> CSR offsets. One 1024-thread block, hierarchical.
// ---------------------------------------------------------------------------
__global__ __launch_bounds__(1024) void scan_kernel(const int* __restrict__ count,
                                                    int* __restrict__ offsets, int n) {
    __shared__ int wsum[16];
    __shared__ int total;
    int t = threadIdx.x;
    const int per = (n + 1023) >> 10;
    int beg = t * per;
    int end = beg + per;
    if (beg > n) beg = n;
    if (end > n) end = n;
    int local[16];
    int s = 0;
    for (int i = beg; i < end; ++i) { int v = count[i]; local[i - beg] = v; s += v; }
    int lane = t & 63, wid = t >> 6;
    int incl = s;
    #pragma unroll
    for (int off = 1; off < 64; off <<= 1) {
        int v = __shfl_up(incl, off, 64);
        if (lane >= off) incl += v;
    }
    if (lane == 63) wsum[wid] = incl;
    __syncthreads();
    if (t == 0) {
        int run = 0;
        #pragma unroll
        for (int w = 0; w < 16; ++w) { int v = wsum[w]; wsum[w] = run; run += v; }
        total = run;
    }
    __syncthreads();
    int base = wsum[wid] + (incl - s);
    for (int i = beg; i < end; ++i) { offsets[i] = base; base += local[i - beg]; }
    if (t == 0) offsets[n] = total;
}

// ---------------------------------------------------------------------------
// 4. Scatter (NO atomics): position = offsets[dst] + precomputed rank.
// ---------------------------------------------------------------------------
__global__ void scatter_kernel(const int* __restrict__ src,
                               const int* __restrict__ dst,
                               const float* __restrict__ e_orig,
                               const int* __restrict__ offsets,
                               const unsigned short* __restrict__ rank,
                               unsigned short* __restrict__ src_sorted,
                               float* __restrict__ e_sorted,
                               int n_edges) {
    int e = blockIdx.x * blockDim.x + threadIdx.x;
    if (e >= n_edges) return;
    int d = dst[e];
    int pos = offsets[d] + (int)rank[e];
    src_sorted[pos] = (unsigned short)src[e];
    e_sorted[pos] = e_orig[e];
}

// ---------------------------------------------------------------------------
// 5. Per-node softmax + aggregation. One wave per node. Per 64-edge chunk:
//    one wave max-reduce + ONE online rescale, then a lean ~9-instr inner
//    loop per edge (broadcasts + exp + coalesced float2 row load + 2 FMA).
// ---------------------------------------------------------------------------
__global__ void agg_kernel(const float* __restrict__ nfeat,
                           const float* __restrict__ norm,
                           const int* __restrict__ offsets,
                           const unsigned short* __restrict__ src_sorted,
                           const float* __restrict__ e_sorted,
                           float* __restrict__ out, int n_nodes) {
    int node = (blockIdx.x * blockDim.x + threadIdx.x) >> 6;
    int lane = threadIdx.x & 63;
    if (node >= n_nodes) return;
    int beg = offsets[node];
    int end = offsets[node + 1];
    const float2* nf2 = (const float2*)nfeat;

    float m = -INFINITY, l = 0.0f, ax = 0.0f, ay = 0.0f;

    for (int base = beg; base < end; base += 64) {
        int nb = end - base;
        if (nb > 64) nb = 64;
        int gi = base + lane;
        bool valid = gi < end;
        int idx = valid ? (int)src_sorted[gi] : 0;
        float ev = valid ? e_sorted[gi] : -INFINITY;
        float nv = norm[idx];

        // chunk max -> single online rescale
        float cm = ev;
        #pragma unroll
        for (int off = 1; off < 64; off <<= 1)
            cm = fmaxf(cm, __shfl_xor(cm, off, 64));
        float m2 = fmaxf(m, cm);
        float scale = expf(m - m2);  // first chunk: exp(-inf) = 0
        ax *= scale; ay *= scale; l *= scale;
        m = m2;

        for (int j = 0; j < nb; ++j) {
            float ej  = __shfl(ev, j, 64);
            int   sj  = __shfl(idx, j, 64);
            float snj = __shfl(nv, j, 64);
            float p = expf(ej - m);
            l += p;
            float w = p * snj;
            float2 f = nf2[sj * 64 + lane];
            ax += w * f.x;
            ay += w * f.y;
        }
    }
    float invl = (l > 0.0f) ? (1.0f / l) : 0.0f;
    ((float2*)out)[node * 64 + lane] = make_float2(ax * invl, ay * invl);
}

// ---------------------------------------------------------------------------
extern "C" void kernel_launch(void* const* d_in, const int* in_sizes, int n_in,
                              void* d_out, int out_size, void* d_ws, size_t ws_size,
                              hipStream_t stream) {
    const float* feat = (const float*)d_in[0];
    const int* src    = (const int*)d_in[1];
    const int* dst    = (const int*)d_in[2];
    const float* beta = (const float*)d_in[3];
    float* out = (float*)d_out;

    const int n_nodes = in_sizes[0] / D_FEAT;
    const int n_edges = in_sizes[1];

    char* ws = (char*)d_ws;
    size_t off = 0;
    auto alloc = [&](size_t bytes) -> void* {
        void* p = ws + off;
        off += (bytes + 255) & ~(size_t)255;
        return p;
    };
    float*          nfeat      = (float*)alloc((size_t)n_nodes * D_FEAT * 4); // 5.12 MB
    float*          norm       = (float*)alloc((size_t)n_nodes * 4);
    int*            count      = (int*)  alloc((size_t)n_nodes * 4);
    int*            offsets    = (int*)  alloc((size_t)(n_nodes + 1) * 4);
    unsigned short* rank       = (unsigned short*)alloc((size_t)n_edges * 2); // 1.28 MB
    float*          e_orig     = (float*)alloc((size_t)n_edges * 4);          // 2.56 MB
    unsigned short* src_sorted = (unsigned short*)alloc((size_t)n_edges * 2); // 1.28 MB
    float*          e_sorted   = (float*)alloc((size_t)n_edges * 4);          // 2.56 MB

    hipMemsetAsync(count, 0, (size_t)n_nodes * sizeof(int), stream);

    normalize_kernel<<<(n_nodes + 3) / 4, 256, 0, stream>>>(feat, nfeat, norm, n_nodes);

    int dot_blocks = (int)(((size_t)n_edges * 8 + 255) / 256);
    dot_rank_kernel<<<dot_blocks, 256, 0, stream>>>(nfeat, src, dst, beta, count,
                                                    rank, e_orig, n_edges);

    scan_kernel<<<1, 1024, 0, stream>>>(count, offsets, n_nodes);

    scatter_kernel<<<(n_edges + 255) / 256, 256, 0, stream>>>(
        src, dst, e_orig, offsets, rank, src_sorted, e_sorted, n_edges);

    agg_kernel<<<(n_nodes + 3) / 4, 256, 0, stream>>>(
        nfeat, norm, offsets, src_sorted, e_sorted, out, n_nodes);
}